// Round 8
// baseline (249.087 us; speedup 1.0000x reference)
//
#include <hip/hip_runtime.h>
#include <hip/hip_bf16.h>
#include <stdint.h>

// Gram matrix: G = X @ X^T, X = [512, 65536] fp32, out = [512, 512] fp32.
// Round 8: K2 GEMM K-loop restructured as an AITER-style async pipeline.
// r5-r7 evidence: the 2-barrier K-loop serializes a ~500-900 cyc global->LDS
// round trip into EVERY iteration (__syncthreads emits s_waitcnt vmcnt(0);
// XCD-affinity only moved hits LLC->L2 and gained ~2us). Fix: quad-buffered
// LDS slabs, depth-3 DMA prefetch, and raw s_waitcnt vmcnt(2n) + s_barrier
// per iter (never vmcnt(0)): slabs it+1,it+2 stay in flight across the
// barrier. Each wave's vmcnt only tracks its own loads, but every wave
// waits for its own slab-it loads before the barrier -> union covers the
// slab. DMA at iter it targets buf (it+3)&3, last read at iter it-1 (reads
// complete before that iter's MFMAs consume them) -> no WAR hazard.
// Tail iters issue clamped dummy loads to keep vmcnt accounting uniform.
// K1 cvt, K3 mirror, atomics epilogue, XCD-affine decode: unchanged (r7).
// Fallback if ws_size < 64 MiB: r1's fused kernel (known-good 135 us).

typedef short bf16x8 __attribute__((ext_vector_type(8)));   // 8 bf16 = 4 VGPRs
typedef float f32x4  __attribute__((ext_vector_type(4)));   // MFMA acc

#define HW    65536
#define CDIM  512

// s_waitcnt imm (CDNA): vmcnt[3:0]=bits3:0, vmcnt[5:4]=bits15:14,
// expcnt=bits6:4, lgkmcnt=bits11:8. "vmcnt(n), ignore exp/lgkm" = 0x0F70|n.
#define WAIT_VMCNT(n) __builtin_amdgcn_s_waitcnt(0x0F70 | (n))

__device__ __forceinline__ short f2bf(float f) {
    __hip_bfloat16 h = __float2bfloat16(f);   // RNE
    short s;
    __builtin_memcpy(&s, &h, sizeof(short));
    return s;
}

__device__ __forceinline__ bf16x8 cvt8(float4 a, float4 b) {
    bf16x8 v;
    v[0] = f2bf(a.x); v[1] = f2bf(a.y); v[2] = f2bf(a.z); v[3] = f2bf(a.w);
    v[4] = f2bf(b.x); v[5] = f2bf(b.y); v[6] = f2bf(b.z); v[7] = f2bf(b.w);
    return v;
}

// async 16B global->LDS copy (DMA; no VGPR round-trip). LDS dest must be
// wave-uniform base + lane*16 — our staging layout is exactly lane-linear.
typedef const __attribute__((address_space(1))) unsigned int gbl_u32;
typedef __attribute__((address_space(3))) unsigned int lds_u32;
__device__ __forceinline__ void async16(const void* g, void* l) {
    __builtin_amdgcn_global_load_lds((gbl_u32*)g, (lds_u32*)l, 16, 0, 0);
}

// ---------------- K1: fp32 -> bf16 convert ----------------
__global__ __launch_bounds__(256)
void cvt_kernel(const float* __restrict__ X, unsigned short* __restrict__ Xb) {
    const size_t i = ((size_t)blockIdx.x * 256 + threadIdx.x) * 8;
    float4 a = *(const float4*)(X + i);
    float4 b = *(const float4*)(X + i + 4);
    bf16x8 v = cvt8(a, b);
    *(bf16x8*)(Xb + i) = v;
}

// ---------------- K2: symmetric bf16 GEMM, async-pipelined ----------------
__global__ __launch_bounds__(256, 2)
void gram_bf16_kernel(const unsigned short* __restrict__ Xb,
                      float* __restrict__ out) {
    // XCD-affine decode (r7): p = 8*q + x; blocks sharing x work the same
    // 1024-col K-slice on XCD x -> panel slice is L2-resident.
    const int p = blockIdx.x;
    const int x = p & 7;
    const int q = p >> 3;
    int tile, k;
    if (q < 40) { k = q / 10; tile = q % 10; }
    else        { const int r = q - 40; k = 4 + r / 6; tile = 4 + r % 6; }

    int ti, tj, iters;
    if (tile < 4) {               // diag: chunks {c, c+32}, 64 iters
        ti = tj = tile;
        iters = 64;
    } else {                      // upper off-diag: one chunk, 32 iters
        const int TI[6] = {0, 0, 0, 1, 1, 2};
        const int TJ[6] = {1, 2, 3, 2, 3, 3};
        ti = TI[tile - 4]; tj = TJ[tile - 4];
        iters = 32;
    }
    const int kslice = (x + 8 * k) * 1024;    // base 1024-col chunk
    const bool diag = (tile < 4);

    // quad-buffered slabs (8 KB each panel-slab), unpadded lane-linear
    __shared__ __align__(16) unsigned short As[4][128 * 32];
    __shared__ __align__(16) unsigned short Bs[4][128 * 32];

    const int t    = threadIdx.x;
    const int wave = t >> 6;
    const int lane = t & 63;
    const int wm   = wave & 1;                // 2x2 wave grid, 64x64 out each
    const int wn   = wave >> 1;
    const int fm   = lane & 15;
    const int kg   = lane >> 4;

    // staging: thread t covers LDS bytes t*16 (rows 0..63) and t*16+4096
    // (rows 64..127); row = t>>2, col8 = (t&3)*8 bf16.
    const int srow = t >> 2;
    const int scol = (t & 3) * 8;
    const int sofs = srow * 32 + scol;              // shorts; byte ofs = t*16
    const unsigned short* gA = Xb + (size_t)(ti * 128 + srow) * HW + scol;
    const unsigned short* gB = Xb + (size_t)(tj * 128 + srow) * HW + scol;
    const size_t rstep = (size_t)64 * HW;           // +64 panel rows

    // fragment offsets (A-operand: m = lane&15, k-group = lane>>4, 8 bf16)
    int a_off[4], b_off[4];
#pragma unroll
    for (int i = 0; i < 4; ++i) {
        a_off[i] = (wm * 64 + i * 16 + fm) * 32 + kg * 8;
        b_off[i] = (wn * 64 + i * 16 + fm) * 32 + kg * 8;
    }

    f32x4 acc[4][4];
#pragma unroll
    for (int i = 0; i < 4; ++i)
#pragma unroll
        for (int j = 0; j < 4; ++j)
            acc[i][j] = (f32x4){0.f, 0.f, 0.f, 0.f};

    // slab s -> global col offset (diag: s 0..63 spans chunks {c, c+32})
    // issue exactly n loads per slab (n=2 diag, n=4 upper), clamped at tail
    // so vmcnt arithmetic stays uniform.
#define ISSUE_SLAB(s_)                                                     \
    do {                                                                   \
        const int ss   = ((s_) < iters) ? (s_) : (iters - 1);              \
        const int bidx = (s_) & 3;                                         \
        const int ko   = kslice + ((ss & 31) << 5) + ((ss >> 5) << 15);    \
        async16(gA + ko,         &As[bidx][sofs]);                         \
        async16(gA + ko + rstep, &As[bidx][sofs + 64 * 32]);               \
        if (!diag) {                                                       \
            async16(gB + ko,         &Bs[bidx][sofs]);                     \
            async16(gB + ko + rstep, &Bs[bidx][sofs + 64 * 32]);           \
        }                                                                  \
    } while (0)

    ISSUE_SLAB(0);
    ISSUE_SLAB(1);
    ISSUE_SLAB(2);

    for (int it = 0; it < iters; ++it) {
        // wait: slab it arrived (2 newer slabs = 2n loads may stay in flight)
        if (diag) WAIT_VMCNT(4);
        else      WAIT_VMCNT(8);
        __builtin_amdgcn_s_barrier();   // raw barrier: NO vmcnt(0) drain

        ISSUE_SLAB(it + 3);             // into buf (it+3)&3 (read at it-1, done)

        const unsigned short* Ab = As[it & 3];
        const unsigned short* Bb = diag ? As[it & 3] : Bs[it & 3];

        bf16x8 af[4], bfr[4];
#pragma unroll
        for (int i = 0; i < 4; ++i) af[i]  = *(const bf16x8*)(Ab + a_off[i]);
#pragma unroll
        for (int j = 0; j < 4; ++j) bfr[j] = *(const bf16x8*)(Bb + b_off[j]);

#pragma unroll
        for (int i = 0; i < 4; ++i)
#pragma unroll
            for (int j = 0; j < 4; ++j)
                acc[i][j] = __builtin_amdgcn_mfma_f32_16x16x32_bf16(
                    af[i], bfr[j], acc[i][j], 0, 0, 0);
        // no trailing barrier: ds_reads complete before their MFMAs issue,
        // and the next iter's barrier gates the buffer overwrite.
    }
#undef ISSUE_SLAB

    // epilogue: row-major coalesced atomics (upper/diag tiles only)
    // C/D layout (verified m89/m91): col = lane&15, row = (lane>>4)*4 + reg
    const int orow0 = ti * 128 + wm * 64 + (lane >> 4) * 4;
    const int ocol0 = tj * 128 + wn * 64 + fm;
#pragma unroll
    for (int i = 0; i < 4; ++i)
#pragma unroll
        for (int j = 0; j < 4; ++j)
#pragma unroll
            for (int r = 0; r < 4; ++r)
                atomicAdd(out + (orow0 + i * 16 + r) * CDIM + ocol0 + j * 16,
                          acc[i][j][r]);
}

// ---------------- K3: mirror upper -> lower ----------------
__global__ __launch_bounds__(256)
void mirror_kernel(float* __restrict__ out) {
    const int id = blockIdx.x * 256 + threadIdx.x;   // 0..262143
    const int r = id >> 9;
    const int c = id & 511;
    if ((r >> 7) > (c >> 7))
        out[id] = out[c * CDIM + r];
}

// ---------------- fallback: r1 fused kernel (known-good 135 us) ----------------
#define FKC   2048
#define FBK   32
#define FLDSS 40

__global__ __launch_bounds__(256, 2)
void gram_fallback(const float* __restrict__ X, float* __restrict__ out) {
    const int tile  = blockIdx.x;
    const int ti    = tile >> 2;
    const int tj    = tile & 3;
    const int chunk = blockIdx.y;

    __shared__ short As[128 * FLDSS];
    __shared__ short Bs[128 * FLDSS];

    const int t    = threadIdx.x;
    const int wave = t >> 6;
    const int lane = t & 63;
    const int wm   = wave & 1;
    const int wn   = wave >> 1;

    const int srow  = t >> 1;
    const int shalf = (t & 1) * 16;
    const float* pa = X + (size_t)(ti * 128 + srow) * HW + chunk * FKC + shalf;
    const float* pb = X + (size_t)(tj * 128 + srow) * HW + chunk * FKC + shalf;
    short* wa = As + srow * FLDSS + shalf;
    short* wb = Bs + srow * FLDSS + shalf;

    const int fm = lane & 15;
    const int kg = lane >> 4;
    int a_off[4], b_off[4];
#pragma unroll
    for (int i = 0; i < 4; ++i) {
        a_off[i] = (wm * 64 + i * 16 + fm) * FLDSS + kg * 8;
        b_off[i] = (wn * 64 + i * 16 + fm) * FLDSS + kg * 8;
    }

    f32x4 acc[4][4];
#pragma unroll
    for (int i = 0; i < 4; ++i)
#pragma unroll
        for (int j = 0; j < 4; ++j)
            acc[i][j] = (f32x4){0.f, 0.f, 0.f, 0.f};

    for (int it = 0; it < FKC / FBK; ++it) {
        float4 a0 = *(const float4*)(pa + 0);
        float4 a1 = *(const float4*)(pa + 4);
        float4 a2 = *(const float4*)(pa + 8);
        float4 a3 = *(const float4*)(pa + 12);
        float4 b0 = *(const float4*)(pb + 0);
        float4 b1 = *(const float4*)(pb + 4);
        float4 b2 = *(const float4*)(pb + 8);
        float4 b3 = *(const float4*)(pb + 12);

        bf16x8 va0 = cvt8(a0, a1), va1 = cvt8(a2, a3);
        bf16x8 vb0 = cvt8(b0, b1), vb1 = cvt8(b2, b3);

        __syncthreads();
        *(bf16x8*)(wa + 0) = va0;
        *(bf16x8*)(wa + 8) = va1;
        *(bf16x8*)(wb + 0) = vb0;
        *(bf16x8*)(wb + 8) = vb1;
        __syncthreads();

        bf16x8 af[4], bfr[4];
#pragma unroll
        for (int i = 0; i < 4; ++i) af[i]  = *(const bf16x8*)(As + a_off[i]);
#pragma unroll
        for (int j = 0; j < 4; ++j) bfr[j] = *(const bf16x8*)(Bs + b_off[j]);

#pragma unroll
        for (int i = 0; i < 4; ++i)
#pragma unroll
            for (int j = 0; j < 4; ++j)
                acc[i][j] = __builtin_amdgcn_mfma_f32_16x16x32_bf16(
                    af[i], bfr[j], acc[i][j], 0, 0, 0);

        pa += FBK;
        pb += FBK;
    }

    const int orow0 = ti * 128 + wm * 64 + (lane >> 4) * 4;
    const int ocol0 = tj * 128 + wn * 64 + fm;
#pragma unroll
    for (int i = 0; i < 4; ++i)
#pragma unroll
        for (int j = 0; j < 4; ++j)
#pragma unroll
            for (int r = 0; r < 4; ++r)
                atomicAdd(out + (orow0 + i * 16 + r) * CDIM + ocol0 + j * 16,
                          acc[i][j][r]);
}

extern "C" void kernel_launch(void* const* d_in, const int* in_sizes, int n_in,
                              void* d_out, int out_size, void* d_ws, size_t ws_size,
                              hipStream_t stream) {
    const float* x = (const float*)d_in[0];
    float* out = (float*)d_out;
    const size_t need = (size_t)CDIM * HW * 2;   // 67,108,864 B bf16 copy

    hipMemsetAsync(d_out, 0, (size_t)out_size * sizeof(float), stream);

    if (ws_size >= need) {
        unsigned short* xb = (unsigned short*)d_ws;
        cvt_kernel<<<dim3(16384), dim3(256), 0, stream>>>(x, xb);
        gram_bf16_kernel<<<dim3(512), dim3(256), 0, stream>>>(xb, out);
        mirror_kernel<<<dim3(1024), dim3(256), 0, stream>>>(out);
    } else {
        gram_fallback<<<dim3(16, 32), dim3(256), 0, stream>>>(x, out);
    }
}